// Round 10
// baseline (483.404 us; speedup 1.0000x reference)
//
#include <hip/hip_runtime.h>
#include <hip/hip_bf16.h>
#include <math.h>

#define FEAT 64
#define NB_PAD 512          // padded bucket count (nodes/bucket = 256)

// ---- bf16 helpers (RNE pack, exact unpack) --------------------------------
__device__ __forceinline__ float bf_lo(unsigned u) { return __uint_as_float(u << 16); }
__device__ __forceinline__ float bf_hi(unsigned u) { return __uint_as_float(u & 0xFFFF0000u); }
__device__ __forceinline__ unsigned short f2bf(float f) {
    unsigned b = __float_as_uint(f);
    return (unsigned short)((b + 0x7FFFu + ((b >> 16) & 1u)) >> 16);
}
__device__ __forceinline__ unsigned pack_exact(float lo, float hi) {
    return (__float_as_uint(lo) >> 16) | (__float_as_uint(hi) & 0xFFFF0000u);
}

// ---------------------------------------------------------------------------
__global__ void zero_kernel(int* __restrict__ p, int n) {
    int i = blockIdx.x * blockDim.x + threadIdx.x;
    if (i < n) p[i] = 0;
}

// ---------------------------------------------------------------------------
// Stage 1: global bucket histogram (bucket = dst >> 8), per-block LDS hist.
// ---------------------------------------------------------------------------
__global__ __launch_bounds__(256) void hist_kernel(const int* __restrict__ dst,
                                                   int* __restrict__ bktCnt, int nE) {
    __shared__ int hist[NB_PAD];
    int t = threadIdx.x;
    hist[t] = 0; hist[t + 256] = 0;
    __syncthreads();
    int chunk = (nE + gridDim.x - 1) / gridDim.x;
    int begin = blockIdx.x * chunk;
    int end = begin + chunk; if (end > nE) end = nE;
    for (int i = begin + t; i < end; i += 256)
        atomicAdd(&hist[dst[i] >> 8], 1);
    __syncthreads();
    if (hist[t])       atomicAdd(&bktCnt[t], hist[t]);
    if (hist[t + 256]) atomicAdd(&bktCnt[t + 256], hist[t + 256]);
}

// ---------------------------------------------------------------------------
// Stage 2: exclusive scan of NB_PAD bucket counts -> bktBase, init bktCursor.
// ---------------------------------------------------------------------------
__global__ void bucket_scan_kernel(const int* __restrict__ bktCnt,
                                   int* __restrict__ bktBase,
                                   int* __restrict__ bktCursor) {
    __shared__ int wsum[4];
    int t = threadIdx.x;
    int d0 = bktCnt[2 * t], d1 = bktCnt[2 * t + 1];
    int ps = d0 + d1;
    int lane = t & 63, w = t >> 6;
    int inc = ps;
    for (int d = 1; d < 64; d <<= 1) { int tt = __shfl_up(inc, d); if (lane >= d) inc += tt; }
    if (lane == 63) wsum[w] = inc;
    __syncthreads();
    if (t == 0) { int r = 0; for (int k = 0; k < 4; ++k) { int v = wsum[k]; wsum[k] = r; r += v; } }
    __syncthreads();
    int pexc = (inc - ps) + wsum[w];
    bktBase[2 * t] = pexc;        bktCursor[2 * t] = pexc;
    bktBase[2 * t + 1] = pexc + d0; bktCursor[2 * t + 1] = pexc + d0;
}

// ---------------------------------------------------------------------------
// Stage 3: partition edges into per-bucket (src,dst) pair arrays.
// ---------------------------------------------------------------------------
__global__ __launch_bounds__(256) void partition_kernel(const int* __restrict__ src,
                                                        const int* __restrict__ dst,
                                                        int* __restrict__ bktCursor,
                                                        uint2* __restrict__ pairs, int nE) {
    __shared__ int hist[NB_PAD];
    __shared__ int lofs[NB_PAD];
    int t = threadIdx.x;
    hist[t] = 0; hist[t + 256] = 0;
    __syncthreads();
    int chunk = (nE + gridDim.x - 1) / gridDim.x;
    int begin = blockIdx.x * chunk;
    int end = begin + chunk; if (end > nE) end = nE;
    for (int i = begin + t; i < end; i += 256)
        atomicAdd(&hist[dst[i] >> 8], 1);
    __syncthreads();
    int c0 = hist[t], c1 = hist[t + 256];
    lofs[t]       = c0 ? atomicAdd(&bktCursor[t], c0) : 0;
    lofs[t + 256] = c1 ? atomicAdd(&bktCursor[t + 256], c1) : 0;
    __syncthreads();
    for (int i = begin + t; i < end; i += 256) {
        int d = dst[i];
        int pos = atomicAdd(&lofs[d >> 8], 1);
        pairs[pos] = make_uint2((unsigned)src[i], (unsigned)d);
    }
}

// ---------------------------------------------------------------------------
// Stage 4: per-bucket CSR finalize.
// ---------------------------------------------------------------------------
__global__ __launch_bounds__(256) void csr_bucket_kernel(const uint2* __restrict__ pairs,
                                                         const int* __restrict__ bktBase,
                                                         int* __restrict__ off,
                                                         int* __restrict__ csr,
                                                         int N, int E) {
    __shared__ int deg[256];
    __shared__ int cur[256];
    __shared__ int wsum[4];
    int b = blockIdx.x;
    int t = threadIdx.x;
    int lo = b << 8;
    int nloc = N - lo; if (nloc > 256) nloc = 256;
    int e0 = bktBase[b], e1 = bktBase[b + 1];
    deg[t] = 0;
    __syncthreads();
    for (int e = e0 + t; e < e1; e += 256)
        atomicAdd(&deg[(int)pairs[e].y - lo], 1);
    __syncthreads();
    int v = deg[t];
    int lane = t & 63, w = t >> 6;
    int inc = v;
    for (int d = 1; d < 64; d <<= 1) { int tt = __shfl_up(inc, d); if (lane >= d) inc += tt; }
    if (lane == 63) wsum[w] = inc;
    __syncthreads();
    if (t == 0) { int r = 0; for (int k = 0; k < 4; ++k) { int x = wsum[k]; wsum[k] = r; r += x; } }
    __syncthreads();
    int excl = (inc - v) + wsum[w];
    if (t < nloc) off[lo + t] = e0 + excl;
    cur[t] = excl;
    if (b == 0 && t == 0) off[N] = E;
    __syncthreads();
    for (int e = e0 + t; e < e1; e += 256) {
        uint2 p = pairs[e];
        int pos = atomicAdd(&cur[(int)p.y - lo], 1);
        csr[e0 + pos] = (int)p.x;
    }
}

// ---------------------------------------------------------------------------
// prep: Wc = Wr+Ws, bias = bl+bs (f32)
// ---------------------------------------------------------------------------
__global__ void prep_kernel(const float* __restrict__ Wr0, const float* __restrict__ Ws0,
                            const float* __restrict__ bl0, const float* __restrict__ bs0,
                            const float* __restrict__ Wr1, const float* __restrict__ Ws1,
                            const float* __restrict__ bl1, const float* __restrict__ bs1,
                            const float* __restrict__ Wr2, const float* __restrict__ Ws2,
                            const float* __restrict__ bl2, const float* __restrict__ bs2,
                            float* __restrict__ wc, float* __restrict__ bias) {
    int i = blockIdx.x * blockDim.x + threadIdx.x;
    if (i < 3 * FEAT * FEAT) {
        int li = i >> 12, j = i & 4095;
        const float* Wr = (li == 0) ? Wr0 : (li == 1) ? Wr1 : Wr2;
        const float* Ws = (li == 0) ? Ws0 : (li == 1) ? Ws1 : Ws2;
        wc[i] = Wr[j] + Ws[j];
    }
    if (i < 3 * FEAT) {
        int li = i >> 6, j = i & 63;
        const float* bl = (li == 0) ? bl0 : (li == 1) ? bl1 : bl2;
        const float* bs = (li == 0) ? bs0 : (li == 1) ? bs1 : bs2;
        bias[i] = bl[j] + bs[j];
    }
}

// ---------------------------------------------------------------------------
// x (f32) -> xb (bf16), 8 elems/thread
// ---------------------------------------------------------------------------
__global__ __launch_bounds__(256) void conv_kernel(const float* __restrict__ in,
                                                   unsigned short* __restrict__ outb,
                                                   int nElem) {
    int base = (blockIdx.x * blockDim.x + threadIdx.x) * 8;
    if (base >= nElem) return;
    float4 a = *(const float4*)(in + base);
    float4 b = *(const float4*)(in + base + 4);
    ushort4 p0 = {f2bf(a.x), f2bf(a.y), f2bf(a.z), f2bf(a.w)};
    ushort4 p1 = {f2bf(b.x), f2bf(b.y), f2bf(b.z), f2bf(b.w)};
    *(ushort4*)(outb + base) = p0;
    *(ushort4*)(outb + base + 4) = p1;
}

// ---------------------------------------------------------------------------
// Max-aggregation on bf16 rows (128 B/row): 8-lane group per node.
// ---------------------------------------------------------------------------
__global__ __launch_bounds__(256) void agg_kernel(const unsigned short* __restrict__ hb,
                                                  const int* __restrict__ off,
                                                  const int* __restrict__ csr_src,
                                                  unsigned short* __restrict__ ab,
                                                  int nNodes) {
    int gid = blockIdx.x * blockDim.x + threadIdx.x;
    int n = gid >> 3;
    int q = gid & 7;
    if (n >= nNodes) return;

    int e0 = off[n], e1 = off[n + 1];
    const float NEG = -INFINITY;
    float acc[8] = {NEG, NEG, NEG, NEG, NEG, NEG, NEG, NEG};

    int e = e0;
    for (; e + 4 <= e1; e += 4) {
        int s0 = csr_src[e], s1 = csr_src[e + 1], s2 = csr_src[e + 2], s3 = csr_src[e + 3];
        uint4 v0 = *(const uint4*)&hb[(size_t)s0 * FEAT + q * 8];
        uint4 v1 = *(const uint4*)&hb[(size_t)s1 * FEAT + q * 8];
        uint4 v2 = *(const uint4*)&hb[(size_t)s2 * FEAT + q * 8];
        uint4 v3 = *(const uint4*)&hb[(size_t)s3 * FEAT + q * 8];
#define ACCUM(v)                                            \
        acc[0] = fmaxf(acc[0], bf_lo(v.x)); acc[1] = fmaxf(acc[1], bf_hi(v.x)); \
        acc[2] = fmaxf(acc[2], bf_lo(v.y)); acc[3] = fmaxf(acc[3], bf_hi(v.y)); \
        acc[4] = fmaxf(acc[4], bf_lo(v.z)); acc[5] = fmaxf(acc[5], bf_hi(v.z)); \
        acc[6] = fmaxf(acc[6], bf_lo(v.w)); acc[7] = fmaxf(acc[7], bf_hi(v.w));
        ACCUM(v0) ACCUM(v1) ACCUM(v2) ACCUM(v3)
    }
    for (; e < e1; ++e) {
        int s0 = csr_src[e];
        uint4 v0 = *(const uint4*)&hb[(size_t)s0 * FEAT + q * 8];
        ACCUM(v0)
    }
#undef ACCUM

    uint4 outv;
    if (e1 > e0) {
        outv.x = pack_exact(acc[0], acc[1]);
        outv.y = pack_exact(acc[2], acc[3]);
        outv.z = pack_exact(acc[4], acc[5]);
        outv.w = pack_exact(acc[6], acc[7]);
    } else {
        outv = make_uint4(0, 0, 0, 0);
    }
    *(uint4*)&ab[(size_t)n * FEAT + q * 8] = outv;
}

// ---------------------------------------------------------------------------
// Transform: relu(agg @ Wl^T + h @ Wc^T + bias). thread = node.
// Block = (256-node tile) x (16-feature quarter): grid 4x larger, LDS 8.3 KB,
// acc[16]/thread -> high occupancy. Weights in LDS, wave-uniform broadcast.
// ---------------------------------------------------------------------------
template <bool BF16OUT>
__global__ __launch_bounds__(256) void transform_kernel(const unsigned short* __restrict__ hb,
                                                        const unsigned short* __restrict__ ab,
                                                        const float* __restrict__ Wl,
                                                        const float* __restrict__ Wc,
                                                        const float* __restrict__ bias,
                                                        float* __restrict__ outf,
                                                        unsigned short* __restrict__ outb,
                                                        int nNodes) {
    __shared__ __align__(16) float wl_s[16 * FEAT];
    __shared__ __align__(16) float wc_s[16 * FEAT];
    __shared__ __align__(16) float b_s[16];

    int tid  = threadIdx.x;
    int tile = blockIdx.x >> 2;
    int fq   = (blockIdx.x & 3) * 16;      // feature quarter (uniform per block)

    // stage 16 rows of Wl and Wc: 1024 floats each = 256 float4 -> 1/thread
    {
        int idx = tid * 4;
        *(float4*)&wl_s[idx] = *(const float4*)&Wl[fq * FEAT + idx];
        *(float4*)&wc_s[idx] = *(const float4*)&Wc[fq * FEAT + idx];
        if (tid < 16) b_s[tid] = bias[fq + tid];
    }
    __syncthreads();

    int n = tile * 256 + tid;
    bool valid = (n < nNodes);
    int nc = valid ? n : (nNodes - 1);
    const unsigned short* __restrict__ ar = ab + (size_t)nc * FEAT;
    const unsigned short* __restrict__ hr = hb + (size_t)nc * FEAT;

    float acc[16];
#pragma unroll
    for (int f = 0; f < 16; ++f) acc[f] = b_s[f];

#pragma unroll 1
    for (int kc = 0; kc < FEAT; kc += 8) {
        uint4 au = *(const uint4*)(ar + kc);
        uint4 hu = *(const uint4*)(hr + kc);
        float ra[8] = {bf_lo(au.x), bf_hi(au.x), bf_lo(au.y), bf_hi(au.y),
                       bf_lo(au.z), bf_hi(au.z), bf_lo(au.w), bf_hi(au.w)};
        float rh[8] = {bf_lo(hu.x), bf_hi(hu.x), bf_lo(hu.y), bf_hi(hu.y),
                       bf_lo(hu.z), bf_hi(hu.z), bf_lo(hu.w), bf_hi(hu.w)};
#pragma unroll
        for (int f = 0; f < 16; ++f) {
            float4 wl0 = *(const float4*)&wl_s[f * FEAT + kc];
            float4 wl1 = *(const float4*)&wl_s[f * FEAT + kc + 4];
            float4 wc0 = *(const float4*)&wc_s[f * FEAT + kc];
            float4 wc1 = *(const float4*)&wc_s[f * FEAT + kc + 4];
            float a = acc[f];
            a = fmaf(ra[0], wl0.x, a); a = fmaf(ra[1], wl0.y, a);
            a = fmaf(ra[2], wl0.z, a); a = fmaf(ra[3], wl0.w, a);
            a = fmaf(ra[4], wl1.x, a); a = fmaf(ra[5], wl1.y, a);
            a = fmaf(ra[6], wl1.z, a); a = fmaf(ra[7], wl1.w, a);
            a = fmaf(rh[0], wc0.x, a); a = fmaf(rh[1], wc0.y, a);
            a = fmaf(rh[2], wc0.z, a); a = fmaf(rh[3], wc0.w, a);
            a = fmaf(rh[4], wc1.x, a); a = fmaf(rh[5], wc1.y, a);
            a = fmaf(rh[6], wc1.z, a); a = fmaf(rh[7], wc1.w, a);
            acc[f] = a;
        }
    }

    if (valid) {
        if (BF16OUT) {
            unsigned short* __restrict__ orow = outb + (size_t)n * FEAT + fq;
            ushort4 p0 = {f2bf(fmaxf(acc[0],  0.f)), f2bf(fmaxf(acc[1],  0.f)),
                          f2bf(fmaxf(acc[2],  0.f)), f2bf(fmaxf(acc[3],  0.f))};
            ushort4 p1 = {f2bf(fmaxf(acc[4],  0.f)), f2bf(fmaxf(acc[5],  0.f)),
                          f2bf(fmaxf(acc[6],  0.f)), f2bf(fmaxf(acc[7],  0.f))};
            ushort4 p2 = {f2bf(fmaxf(acc[8],  0.f)), f2bf(fmaxf(acc[9],  0.f)),
                          f2bf(fmaxf(acc[10], 0.f)), f2bf(fmaxf(acc[11], 0.f))};
            ushort4 p3 = {f2bf(fmaxf(acc[12], 0.f)), f2bf(fmaxf(acc[13], 0.f)),
                          f2bf(fmaxf(acc[14], 0.f)), f2bf(fmaxf(acc[15], 0.f))};
            *(ushort4*)(orow)      = p0;
            *(ushort4*)(orow + 4)  = p1;
            *(ushort4*)(orow + 8)  = p2;
            *(ushort4*)(orow + 12) = p3;
        } else {
            float* __restrict__ orow = outf + (size_t)n * FEAT + fq;
#pragma unroll
            for (int f = 0; f < 16; f += 4) {
                float4 v = make_float4(fmaxf(acc[f],     0.f), fmaxf(acc[f + 1], 0.f),
                                       fmaxf(acc[f + 2], 0.f), fmaxf(acc[f + 3], 0.f));
                *(float4*)(orow + f) = v;
            }
        }
    }
}

// ---------------------------------------------------------------------------
extern "C" void kernel_launch(void* const* d_in, const int* in_sizes, int n_in,
                              void* d_out, int out_size, void* d_ws, size_t ws_size,
                              hipStream_t stream) {
    const float* x   = (const float*)d_in[0];
    const int* eidx  = (const int*)d_in[1];
    const int N  = in_sizes[0] / FEAT;
    const int E  = in_sizes[1] / 2;
    const int* src = eidx;
    const int* dst = eidx + E;

    const float* Wl[3]; const float* bl[3]; const float* Wr[3];
    const float* Ws[3]; const float* bs[3];
    for (int li = 0; li < 3; ++li) {
        Wl[li] = (const float*)d_in[2 + 5 * li + 0];
        bl[li] = (const float*)d_in[2 + 5 * li + 1];
        Wr[li] = (const float*)d_in[2 + 5 * li + 2];
        Ws[li] = (const float*)d_in[2 + 5 * li + 3];
        bs[li] = (const float*)d_in[2 + 5 * li + 4];
    }

    auto align256 = [](size_t v) { return (v + 255) & ~(size_t)255; };
    char* ws = (char*)d_ws;
    int* off       = (int*)ws;  ws += align256((size_t)(N + 1) * 4);
    int* bktCnt    = (int*)ws;  ws += align256(NB_PAD * 4);
    int* bktBase   = (int*)ws;  ws += align256((NB_PAD + 1) * 4);
    int* bktCursor = (int*)ws;  ws += align256(NB_PAD * 4);
    uint2* pairs   = (uint2*)ws; ws += align256((size_t)E * 8);
    int* csr_src   = (int*)ws;  ws += align256((size_t)E * 4);
    float* wcbuf   = (float*)ws; ws += align256(3 * FEAT * FEAT * 4);
    float* biasbuf = (float*)ws; ws += align256(3 * FEAT * 4);
    unsigned short* xb  = (unsigned short*)ws; ws += align256((size_t)N * FEAT * 2);
    unsigned short* ab  = (unsigned short*)ws; ws += align256((size_t)N * FEAT * 2);
    unsigned short* h1b = (unsigned short*)ws; ws += align256((size_t)N * FEAT * 2);
    unsigned short* h2b = (unsigned short*)ws; ws += align256((size_t)N * FEAT * 2);

    const int TB = 256;
    int nBkt = (N + 255) >> 8;

    // ---- CSR build: hist -> scan -> partition -> per-bucket finalize ----
    zero_kernel<<<2, TB, 0, stream>>>(bktCnt, NB_PAD);
    hist_kernel<<<256, TB, 0, stream>>>(dst, bktCnt, E);
    bucket_scan_kernel<<<1, TB, 0, stream>>>(bktCnt, bktBase, bktCursor);
    partition_kernel<<<256, TB, 0, stream>>>(src, dst, bktCursor, pairs, E);
    csr_bucket_kernel<<<nBkt, TB, 0, stream>>>(pairs, bktBase, off, csr_src, N, E);

    prep_kernel<<<(3 * FEAT * FEAT + TB - 1) / TB, TB, 0, stream>>>(
        Wr[0], Ws[0], bl[0], bs[0], Wr[1], Ws[1], bl[1], bs[1],
        Wr[2], Ws[2], bl[2], bs[2], wcbuf, biasbuf);
    int convBlocks = (N * FEAT / 8 + TB - 1) / TB;
    conv_kernel<<<convBlocks, TB, 0, stream>>>(x, xb, N * FEAT);

    int aggBlocks = (N * 8 + TB - 1) / TB;
    int trfBlocks = ((N + 255) / 256) * 4;     // x4 feature quarters

    // ---- layer 0 ----
    agg_kernel<<<aggBlocks, TB, 0, stream>>>(xb, off, csr_src, ab, N);
    transform_kernel<true><<<trfBlocks, TB, 0, stream>>>(xb, ab, Wl[0], wcbuf + 0 * 4096,
                                                         biasbuf + 0 * 64, nullptr, h1b, N);
    // ---- layer 1 ----
    agg_kernel<<<aggBlocks, TB, 0, stream>>>(h1b, off, csr_src, ab, N);
    transform_kernel<true><<<trfBlocks, TB, 0, stream>>>(h1b, ab, Wl[1], wcbuf + 1 * 4096,
                                                         biasbuf + 1 * 64, nullptr, h2b, N);
    // ---- layer 2 (f32 output) ----
    agg_kernel<<<aggBlocks, TB, 0, stream>>>(h2b, off, csr_src, ab, N);
    transform_kernel<false><<<trfBlocks, TB, 0, stream>>>(h2b, ab, Wl[2], wcbuf + 2 * 4096,
                                                          biasbuf + 2 * 64, (float*)d_out, nullptr, N);
}

// Round 11
// 283.289 us; speedup vs baseline: 1.7064x; 1.7064x over previous
//
#include <hip/hip_runtime.h>
#include <hip/hip_bf16.h>
#include <math.h>

#define FEAT 64
#define NB_PAD 512          // padded bucket count (nodes/bucket = 256)

// ---- bf16 helpers (RNE pack, exact unpack) --------------------------------
__device__ __forceinline__ float bf_lo(unsigned u) { return __uint_as_float(u << 16); }
__device__ __forceinline__ float bf_hi(unsigned u) { return __uint_as_float(u & 0xFFFF0000u); }
__device__ __forceinline__ unsigned short f2bf(float f) {
    unsigned b = __float_as_uint(f);
    return (unsigned short)((b + 0x7FFFu + ((b >> 16) & 1u)) >> 16);
}
__device__ __forceinline__ unsigned pack_exact(float lo, float hi) {
    return (__float_as_uint(lo) >> 16) | (__float_as_uint(hi) & 0xFFFF0000u);
}

// ---------------------------------------------------------------------------
__global__ void zero_kernel(int* __restrict__ p, int n) {
    int i = blockIdx.x * blockDim.x + threadIdx.x;
    if (i < n) p[i] = 0;
}

// ---------------------------------------------------------------------------
// Stage 1: global bucket histogram (bucket = dst >> 8), per-block LDS hist.
// ---------------------------------------------------------------------------
__global__ __launch_bounds__(256) void hist_kernel(const int* __restrict__ dst,
                                                   int* __restrict__ bktCnt, int nE) {
    __shared__ int hist[NB_PAD];
    int t = threadIdx.x;
    hist[t] = 0; hist[t + 256] = 0;
    __syncthreads();
    int chunk = (nE + gridDim.x - 1) / gridDim.x;
    int begin = blockIdx.x * chunk;
    int end = begin + chunk; if (end > nE) end = nE;
    for (int i = begin + t; i < end; i += 256)
        atomicAdd(&hist[dst[i] >> 8], 1);
    __syncthreads();
    if (hist[t])       atomicAdd(&bktCnt[t], hist[t]);
    if (hist[t + 256]) atomicAdd(&bktCnt[t + 256], hist[t + 256]);
}

// ---------------------------------------------------------------------------
// Stage 2: exclusive scan of NB_PAD bucket counts -> bktBase, init bktCursor.
// ---------------------------------------------------------------------------
__global__ void bucket_scan_kernel(const int* __restrict__ bktCnt,
                                   int* __restrict__ bktBase,
                                   int* __restrict__ bktCursor) {
    __shared__ int wsum[4];
    int t = threadIdx.x;
    int d0 = bktCnt[2 * t], d1 = bktCnt[2 * t + 1];
    int ps = d0 + d1;
    int lane = t & 63, w = t >> 6;
    int inc = ps;
    for (int d = 1; d < 64; d <<= 1) { int tt = __shfl_up(inc, d); if (lane >= d) inc += tt; }
    if (lane == 63) wsum[w] = inc;
    __syncthreads();
    if (t == 0) { int r = 0; for (int k = 0; k < 4; ++k) { int v = wsum[k]; wsum[k] = r; r += v; } }
    __syncthreads();
    int pexc = (inc - ps) + wsum[w];
    bktBase[2 * t] = pexc;        bktCursor[2 * t] = pexc;
    bktBase[2 * t + 1] = pexc + d0; bktCursor[2 * t + 1] = pexc + d0;
}

// ---------------------------------------------------------------------------
// Stage 3: partition edges into per-bucket (src,dst) pair arrays.
// ---------------------------------------------------------------------------
__global__ __launch_bounds__(256) void partition_kernel(const int* __restrict__ src,
                                                        const int* __restrict__ dst,
                                                        int* __restrict__ bktCursor,
                                                        uint2* __restrict__ pairs, int nE) {
    __shared__ int hist[NB_PAD];
    __shared__ int lofs[NB_PAD];
    int t = threadIdx.x;
    hist[t] = 0; hist[t + 256] = 0;
    __syncthreads();
    int chunk = (nE + gridDim.x - 1) / gridDim.x;
    int begin = blockIdx.x * chunk;
    int end = begin + chunk; if (end > nE) end = nE;
    for (int i = begin + t; i < end; i += 256)
        atomicAdd(&hist[dst[i] >> 8], 1);
    __syncthreads();
    int c0 = hist[t], c1 = hist[t + 256];
    lofs[t]       = c0 ? atomicAdd(&bktCursor[t], c0) : 0;
    lofs[t + 256] = c1 ? atomicAdd(&bktCursor[t + 256], c1) : 0;
    __syncthreads();
    for (int i = begin + t; i < end; i += 256) {
        int d = dst[i];
        int pos = atomicAdd(&lofs[d >> 8], 1);
        pairs[pos] = make_uint2((unsigned)src[i], (unsigned)d);
    }
}

// ---------------------------------------------------------------------------
// Stage 4: per-bucket CSR finalize.
// ---------------------------------------------------------------------------
__global__ __launch_bounds__(256) void csr_bucket_kernel(const uint2* __restrict__ pairs,
                                                         const int* __restrict__ bktBase,
                                                         int* __restrict__ off,
                                                         int* __restrict__ csr,
                                                         int N, int E) {
    __shared__ int deg[256];
    __shared__ int cur[256];
    __shared__ int wsum[4];
    int b = blockIdx.x;
    int t = threadIdx.x;
    int lo = b << 8;
    int nloc = N - lo; if (nloc > 256) nloc = 256;
    int e0 = bktBase[b], e1 = bktBase[b + 1];
    deg[t] = 0;
    __syncthreads();
    for (int e = e0 + t; e < e1; e += 256)
        atomicAdd(&deg[(int)pairs[e].y - lo], 1);
    __syncthreads();
    int v = deg[t];
    int lane = t & 63, w = t >> 6;
    int inc = v;
    for (int d = 1; d < 64; d <<= 1) { int tt = __shfl_up(inc, d); if (lane >= d) inc += tt; }
    if (lane == 63) wsum[w] = inc;
    __syncthreads();
    if (t == 0) { int r = 0; for (int k = 0; k < 4; ++k) { int x = wsum[k]; wsum[k] = r; r += x; } }
    __syncthreads();
    int excl = (inc - v) + wsum[w];
    if (t < nloc) off[lo + t] = e0 + excl;
    cur[t] = excl;
    if (b == 0 && t == 0) off[N] = E;
    __syncthreads();
    for (int e = e0 + t; e < e1; e += 256) {
        uint2 p = pairs[e];
        int pos = atomicAdd(&cur[(int)p.y - lo], 1);
        csr[e0 + pos] = (int)p.x;
    }
}

// ---------------------------------------------------------------------------
// prep: Wc = Wr+Ws, bias = bl+bs (f32)
// ---------------------------------------------------------------------------
__global__ void prep_kernel(const float* __restrict__ Wr0, const float* __restrict__ Ws0,
                            const float* __restrict__ bl0, const float* __restrict__ bs0,
                            const float* __restrict__ Wr1, const float* __restrict__ Ws1,
                            const float* __restrict__ bl1, const float* __restrict__ bs1,
                            const float* __restrict__ Wr2, const float* __restrict__ Ws2,
                            const float* __restrict__ bl2, const float* __restrict__ bs2,
                            float* __restrict__ wc, float* __restrict__ bias) {
    int i = blockIdx.x * blockDim.x + threadIdx.x;
    if (i < 3 * FEAT * FEAT) {
        int li = i >> 12, j = i & 4095;
        const float* Wr = (li == 0) ? Wr0 : (li == 1) ? Wr1 : Wr2;
        const float* Ws = (li == 0) ? Ws0 : (li == 1) ? Ws1 : Ws2;
        wc[i] = Wr[j] + Ws[j];
    }
    if (i < 3 * FEAT) {
        int li = i >> 6, j = i & 63;
        const float* bl = (li == 0) ? bl0 : (li == 1) ? bl1 : bl2;
        const float* bs = (li == 0) ? bs0 : (li == 1) ? bs1 : bs2;
        bias[i] = bl[j] + bs[j];
    }
}

// ---------------------------------------------------------------------------
// x (f32) -> xb (bf16), 8 elems/thread
// ---------------------------------------------------------------------------
__global__ __launch_bounds__(256) void conv_kernel(const float* __restrict__ in,
                                                   unsigned short* __restrict__ outb,
                                                   int nElem) {
    int base = (blockIdx.x * blockDim.x + threadIdx.x) * 8;
    if (base >= nElem) return;
    float4 a = *(const float4*)(in + base);
    float4 b = *(const float4*)(in + base + 4);
    ushort4 p0 = {f2bf(a.x), f2bf(a.y), f2bf(a.z), f2bf(a.w)};
    ushort4 p1 = {f2bf(b.x), f2bf(b.y), f2bf(b.z), f2bf(b.w)};
    *(ushort4*)(outb + base) = p0;
    *(ushort4*)(outb + base + 4) = p1;
}

// ---------------------------------------------------------------------------
// Max-aggregation on bf16 rows (128 B/row): 8-lane group per node.
// ---------------------------------------------------------------------------
__global__ __launch_bounds__(256) void agg_kernel(const unsigned short* __restrict__ hb,
                                                  const int* __restrict__ off,
                                                  const int* __restrict__ csr_src,
                                                  unsigned short* __restrict__ ab,
                                                  int nNodes) {
    int gid = blockIdx.x * blockDim.x + threadIdx.x;
    int n = gid >> 3;
    int q = gid & 7;
    if (n >= nNodes) return;

    int e0 = off[n], e1 = off[n + 1];
    const float NEG = -INFINITY;
    float acc[8] = {NEG, NEG, NEG, NEG, NEG, NEG, NEG, NEG};

    int e = e0;
    for (; e + 4 <= e1; e += 4) {
        int s0 = csr_src[e], s1 = csr_src[e + 1], s2 = csr_src[e + 2], s3 = csr_src[e + 3];
        uint4 v0 = *(const uint4*)&hb[(size_t)s0 * FEAT + q * 8];
        uint4 v1 = *(const uint4*)&hb[(size_t)s1 * FEAT + q * 8];
        uint4 v2 = *(const uint4*)&hb[(size_t)s2 * FEAT + q * 8];
        uint4 v3 = *(const uint4*)&hb[(size_t)s3 * FEAT + q * 8];
#define ACCUM(v)                                            \
        acc[0] = fmaxf(acc[0], bf_lo(v.x)); acc[1] = fmaxf(acc[1], bf_hi(v.x)); \
        acc[2] = fmaxf(acc[2], bf_lo(v.y)); acc[3] = fmaxf(acc[3], bf_hi(v.y)); \
        acc[4] = fmaxf(acc[4], bf_lo(v.z)); acc[5] = fmaxf(acc[5], bf_hi(v.z)); \
        acc[6] = fmaxf(acc[6], bf_lo(v.w)); acc[7] = fmaxf(acc[7], bf_hi(v.w));
        ACCUM(v0) ACCUM(v1) ACCUM(v2) ACCUM(v3)
    }
    for (; e < e1; ++e) {
        int s0 = csr_src[e];
        uint4 v0 = *(const uint4*)&hb[(size_t)s0 * FEAT + q * 8];
        ACCUM(v0)
    }
#undef ACCUM

    uint4 outv;
    if (e1 > e0) {
        outv.x = pack_exact(acc[0], acc[1]);
        outv.y = pack_exact(acc[2], acc[3]);
        outv.z = pack_exact(acc[4], acc[5]);
        outv.w = pack_exact(acc[6], acc[7]);
    } else {
        outv = make_uint4(0, 0, 0, 0);
    }
    *(uint4*)&ab[(size_t)n * FEAT + q * 8] = outv;
}

// ---------------------------------------------------------------------------
// Transform: relu(agg @ Wl^T + h @ Wc^T + bias). thread = node.
// Block = (256-node tile) x (16-feature quarter) with XCD-AFFINE swizzle:
// xcd = blockIdx&7, and that XCD owns a contiguous range of tiles; all 4
// f-quarter blocks of a tile land on the SAME XCD -> row re-reads are L2-local
// instead of replicated across 8 incoherent L2s (round-10 regression fix).
// ---------------------------------------------------------------------------
template <bool BF16OUT>
__global__ __launch_bounds__(256) void transform_kernel(const unsigned short* __restrict__ hb,
                                                        const unsigned short* __restrict__ ab,
                                                        const float* __restrict__ Wl,
                                                        const float* __restrict__ Wc,
                                                        const float* __restrict__ bias,
                                                        float* __restrict__ outf,
                                                        unsigned short* __restrict__ outb,
                                                        int nNodes, int nTiles, int tpx) {
    __shared__ __align__(16) float wl_s[16 * FEAT];
    __shared__ __align__(16) float wc_s[16 * FEAT];
    __shared__ __align__(16) float b_s[16];

    int b   = blockIdx.x;
    int xcd = b & 7;
    int j   = b >> 3;
    int tile = xcd * tpx + (j >> 2);
    int fq   = (j & 3) * 16;               // feature quarter (uniform per block)
    if (tile >= nTiles) return;

    int tid = threadIdx.x;
    // stage 16 rows of Wl and Wc: 1024 floats each = 256 float4 -> 1/thread
    {
        int idx = tid * 4;
        *(float4*)&wl_s[idx] = *(const float4*)&Wl[fq * FEAT + idx];
        *(float4*)&wc_s[idx] = *(const float4*)&Wc[fq * FEAT + idx];
        if (tid < 16) b_s[tid] = bias[fq + tid];
    }
    __syncthreads();

    int n = tile * 256 + tid;
    bool valid = (n < nNodes);
    int nc = valid ? n : (nNodes - 1);
    const unsigned short* __restrict__ ar = ab + (size_t)nc * FEAT;
    const unsigned short* __restrict__ hr = hb + (size_t)nc * FEAT;

    float acc[16];
#pragma unroll
    for (int f = 0; f < 16; ++f) acc[f] = b_s[f];

#pragma unroll 1
    for (int kc = 0; kc < FEAT; kc += 8) {
        uint4 au = *(const uint4*)(ar + kc);
        uint4 hu = *(const uint4*)(hr + kc);
        float ra[8] = {bf_lo(au.x), bf_hi(au.x), bf_lo(au.y), bf_hi(au.y),
                       bf_lo(au.z), bf_hi(au.z), bf_lo(au.w), bf_hi(au.w)};
        float rh[8] = {bf_lo(hu.x), bf_hi(hu.x), bf_lo(hu.y), bf_hi(hu.y),
                       bf_lo(hu.z), bf_hi(hu.z), bf_lo(hu.w), bf_hi(hu.w)};
#pragma unroll
        for (int f = 0; f < 16; ++f) {
            float4 wl0 = *(const float4*)&wl_s[f * FEAT + kc];
            float4 wl1 = *(const float4*)&wl_s[f * FEAT + kc + 4];
            float4 wc0 = *(const float4*)&wc_s[f * FEAT + kc];
            float4 wc1 = *(const float4*)&wc_s[f * FEAT + kc + 4];
            float a = acc[f];
            a = fmaf(ra[0], wl0.x, a); a = fmaf(ra[1], wl0.y, a);
            a = fmaf(ra[2], wl0.z, a); a = fmaf(ra[3], wl0.w, a);
            a = fmaf(ra[4], wl1.x, a); a = fmaf(ra[5], wl1.y, a);
            a = fmaf(ra[6], wl1.z, a); a = fmaf(ra[7], wl1.w, a);
            a = fmaf(rh[0], wc0.x, a); a = fmaf(rh[1], wc0.y, a);
            a = fmaf(rh[2], wc0.z, a); a = fmaf(rh[3], wc0.w, a);
            a = fmaf(rh[4], wc1.x, a); a = fmaf(rh[5], wc1.y, a);
            a = fmaf(rh[6], wc1.z, a); a = fmaf(rh[7], wc1.w, a);
            acc[f] = a;
        }
    }

    if (valid) {
        if (BF16OUT) {
            unsigned short* __restrict__ orow = outb + (size_t)n * FEAT + fq;
            ushort4 p0 = {f2bf(fmaxf(acc[0],  0.f)), f2bf(fmaxf(acc[1],  0.f)),
                          f2bf(fmaxf(acc[2],  0.f)), f2bf(fmaxf(acc[3],  0.f))};
            ushort4 p1 = {f2bf(fmaxf(acc[4],  0.f)), f2bf(fmaxf(acc[5],  0.f)),
                          f2bf(fmaxf(acc[6],  0.f)), f2bf(fmaxf(acc[7],  0.f))};
            ushort4 p2 = {f2bf(fmaxf(acc[8],  0.f)), f2bf(fmaxf(acc[9],  0.f)),
                          f2bf(fmaxf(acc[10], 0.f)), f2bf(fmaxf(acc[11], 0.f))};
            ushort4 p3 = {f2bf(fmaxf(acc[12], 0.f)), f2bf(fmaxf(acc[13], 0.f)),
                          f2bf(fmaxf(acc[14], 0.f)), f2bf(fmaxf(acc[15], 0.f))};
            *(ushort4*)(orow)      = p0;
            *(ushort4*)(orow + 4)  = p1;
            *(ushort4*)(orow + 8)  = p2;
            *(ushort4*)(orow + 12) = p3;
        } else {
            float* __restrict__ orow = outf + (size_t)n * FEAT + fq;
#pragma unroll
            for (int f = 0; f < 16; f += 4) {
                float4 v = make_float4(fmaxf(acc[f],     0.f), fmaxf(acc[f + 1], 0.f),
                                       fmaxf(acc[f + 2], 0.f), fmaxf(acc[f + 3], 0.f));
                *(float4*)(orow + f) = v;
            }
        }
    }
}

// ---------------------------------------------------------------------------
extern "C" void kernel_launch(void* const* d_in, const int* in_sizes, int n_in,
                              void* d_out, int out_size, void* d_ws, size_t ws_size,
                              hipStream_t stream) {
    const float* x   = (const float*)d_in[0];
    const int* eidx  = (const int*)d_in[1];
    const int N  = in_sizes[0] / FEAT;
    const int E  = in_sizes[1] / 2;
    const int* src = eidx;
    const int* dst = eidx + E;

    const float* Wl[3]; const float* bl[3]; const float* Wr[3];
    const float* Ws[3]; const float* bs[3];
    for (int li = 0; li < 3; ++li) {
        Wl[li] = (const float*)d_in[2 + 5 * li + 0];
        bl[li] = (const float*)d_in[2 + 5 * li + 1];
        Wr[li] = (const float*)d_in[2 + 5 * li + 2];
        Ws[li] = (const float*)d_in[2 + 5 * li + 3];
        bs[li] = (const float*)d_in[2 + 5 * li + 4];
    }

    auto align256 = [](size_t v) { return (v + 255) & ~(size_t)255; };
    char* ws = (char*)d_ws;
    int* off       = (int*)ws;  ws += align256((size_t)(N + 1) * 4);
    int* bktCnt    = (int*)ws;  ws += align256(NB_PAD * 4);
    int* bktBase   = (int*)ws;  ws += align256((NB_PAD + 1) * 4);
    int* bktCursor = (int*)ws;  ws += align256(NB_PAD * 4);
    uint2* pairs   = (uint2*)ws; ws += align256((size_t)E * 8);
    int* csr_src   = (int*)ws;  ws += align256((size_t)E * 4);
    float* wcbuf   = (float*)ws; ws += align256(3 * FEAT * FEAT * 4);
    float* biasbuf = (float*)ws; ws += align256(3 * FEAT * 4);
    unsigned short* xb  = (unsigned short*)ws; ws += align256((size_t)N * FEAT * 2);
    unsigned short* ab  = (unsigned short*)ws; ws += align256((size_t)N * FEAT * 2);
    unsigned short* h1b = (unsigned short*)ws; ws += align256((size_t)N * FEAT * 2);
    unsigned short* h2b = (unsigned short*)ws; ws += align256((size_t)N * FEAT * 2);

    const int TB = 256;
    int nBkt = (N + 255) >> 8;

    // ---- CSR build: hist -> scan -> partition -> per-bucket finalize ----
    zero_kernel<<<2, TB, 0, stream>>>(bktCnt, NB_PAD);
    hist_kernel<<<256, TB, 0, stream>>>(dst, bktCnt, E);
    bucket_scan_kernel<<<1, TB, 0, stream>>>(bktCnt, bktBase, bktCursor);
    partition_kernel<<<256, TB, 0, stream>>>(src, dst, bktCursor, pairs, E);
    csr_bucket_kernel<<<nBkt, TB, 0, stream>>>(pairs, bktBase, off, csr_src, N, E);

    prep_kernel<<<(3 * FEAT * FEAT + TB - 1) / TB, TB, 0, stream>>>(
        Wr[0], Ws[0], bl[0], bs[0], Wr[1], Ws[1], bl[1], bs[1],
        Wr[2], Ws[2], bl[2], bs[2], wcbuf, biasbuf);
    int convBlocks = (N * FEAT / 8 + TB - 1) / TB;
    conv_kernel<<<convBlocks, TB, 0, stream>>>(x, xb, N * FEAT);

    int aggBlocks = (N * 8 + TB - 1) / TB;
    int nTiles = (N + 255) / 256;
    int tpx = (nTiles + 7) / 8;            // tiles per XCD
    int trfBlocks = 8 * tpx * 4;           // xcd-affine swizzled grid

    // ---- layer 0 ----
    agg_kernel<<<aggBlocks, TB, 0, stream>>>(xb, off, csr_src, ab, N);
    transform_kernel<true><<<trfBlocks, TB, 0, stream>>>(xb, ab, Wl[0], wcbuf + 0 * 4096,
                                                         biasbuf + 0 * 64, nullptr, h1b, N, nTiles, tpx);
    // ---- layer 1 ----
    agg_kernel<<<aggBlocks, TB, 0, stream>>>(h1b, off, csr_src, ab, N);
    transform_kernel<true><<<trfBlocks, TB, 0, stream>>>(h1b, ab, Wl[1], wcbuf + 1 * 4096,
                                                         biasbuf + 1 * 64, nullptr, h2b, N, nTiles, tpx);
    // ---- layer 2 (f32 output) ----
    agg_kernel<<<aggBlocks, TB, 0, stream>>>(h2b, off, csr_src, ab, N);
    transform_kernel<false><<<trfBlocks, TB, 0, stream>>>(h2b, ab, Wl[2], wcbuf + 2 * 4096,
                                                          biasbuf + 2 * 64, (float*)d_out, nullptr, N, nTiles, tpx);
}

// Round 12
// 218.158 us; speedup vs baseline: 2.2158x; 1.2986x over previous
//
#include <hip/hip_runtime.h>
#include <hip/hip_bf16.h>
#include <math.h>

#define FEAT 64
#define NB_PAD 512          // padded bucket count (nodes/bucket = 256)

typedef __attribute__((ext_vector_type(8))) short short8;   // 8 bf16 (4 VGPRs)
typedef __attribute__((ext_vector_type(4))) float f32x4;    // MFMA C/D

// ---- bf16 helpers (RNE pack, exact unpack) --------------------------------
__device__ __forceinline__ float bf_lo(unsigned u) { return __uint_as_float(u << 16); }
__device__ __forceinline__ float bf_hi(unsigned u) { return __uint_as_float(u & 0xFFFF0000u); }
__device__ __forceinline__ unsigned short f2bf(float f) {
    unsigned b = __float_as_uint(f);
    return (unsigned short)((b + 0x7FFFu + ((b >> 16) & 1u)) >> 16);
}
__device__ __forceinline__ unsigned pack_exact(float lo, float hi) {
    return (__float_as_uint(lo) >> 16) | (__float_as_uint(hi) & 0xFFFF0000u);
}

// ---------------------------------------------------------------------------
__global__ void zero_kernel(int* __restrict__ p, int n) {
    int i = blockIdx.x * blockDim.x + threadIdx.x;
    if (i < n) p[i] = 0;
}

// ---------------------------------------------------------------------------
// Stage 1: global bucket histogram (bucket = dst >> 8), per-block LDS hist.
// ---------------------------------------------------------------------------
__global__ __launch_bounds__(256) void hist_kernel(const int* __restrict__ dst,
                                                   int* __restrict__ bktCnt, int nE) {
    __shared__ int hist[NB_PAD];
    int t = threadIdx.x;
    hist[t] = 0; hist[t + 256] = 0;
    __syncthreads();
    int chunk = (nE + gridDim.x - 1) / gridDim.x;
    int begin = blockIdx.x * chunk;
    int end = begin + chunk; if (end > nE) end = nE;
    for (int i = begin + t; i < end; i += 256)
        atomicAdd(&hist[dst[i] >> 8], 1);
    __syncthreads();
    if (hist[t])       atomicAdd(&bktCnt[t], hist[t]);
    if (hist[t + 256]) atomicAdd(&bktCnt[t + 256], hist[t + 256]);
}

// ---------------------------------------------------------------------------
// Stage 2: exclusive scan of NB_PAD bucket counts -> bktBase, init bktCursor.
// ---------------------------------------------------------------------------
__global__ void bucket_scan_kernel(const int* __restrict__ bktCnt,
                                   int* __restrict__ bktBase,
                                   int* __restrict__ bktCursor) {
    __shared__ int wsum[4];
    int t = threadIdx.x;
    int d0 = bktCnt[2 * t], d1 = bktCnt[2 * t + 1];
    int ps = d0 + d1;
    int lane = t & 63, w = t >> 6;
    int inc = ps;
    for (int d = 1; d < 64; d <<= 1) { int tt = __shfl_up(inc, d); if (lane >= d) inc += tt; }
    if (lane == 63) wsum[w] = inc;
    __syncthreads();
    if (t == 0) { int r = 0; for (int k = 0; k < 4; ++k) { int v = wsum[k]; wsum[k] = r; r += v; } }
    __syncthreads();
    int pexc = (inc - ps) + wsum[w];
    bktBase[2 * t] = pexc;        bktCursor[2 * t] = pexc;
    bktBase[2 * t + 1] = pexc + d0; bktCursor[2 * t + 1] = pexc + d0;
}

// ---------------------------------------------------------------------------
// Stage 3: partition edges into per-bucket (src,dst) pair arrays.
// ---------------------------------------------------------------------------
__global__ __launch_bounds__(256) void partition_kernel(const int* __restrict__ src,
                                                        const int* __restrict__ dst,
                                                        int* __restrict__ bktCursor,
                                                        uint2* __restrict__ pairs, int nE) {
    __shared__ int hist[NB_PAD];
    __shared__ int lofs[NB_PAD];
    int t = threadIdx.x;
    hist[t] = 0; hist[t + 256] = 0;
    __syncthreads();
    int chunk = (nE + gridDim.x - 1) / gridDim.x;
    int begin = blockIdx.x * chunk;
    int end = begin + chunk; if (end > nE) end = nE;
    for (int i = begin + t; i < end; i += 256)
        atomicAdd(&hist[dst[i] >> 8], 1);
    __syncthreads();
    int c0 = hist[t], c1 = hist[t + 256];
    lofs[t]       = c0 ? atomicAdd(&bktCursor[t], c0) : 0;
    lofs[t + 256] = c1 ? atomicAdd(&bktCursor[t + 256], c1) : 0;
    __syncthreads();
    for (int i = begin + t; i < end; i += 256) {
        int d = dst[i];
        int pos = atomicAdd(&lofs[d >> 8], 1);
        pairs[pos] = make_uint2((unsigned)src[i], (unsigned)d);
    }
}

// ---------------------------------------------------------------------------
// Stage 4: per-bucket CSR finalize.
// ---------------------------------------------------------------------------
__global__ __launch_bounds__(256) void csr_bucket_kernel(const uint2* __restrict__ pairs,
                                                         const int* __restrict__ bktBase,
                                                         int* __restrict__ off,
                                                         int* __restrict__ csr,
                                                         int N, int E) {
    __shared__ int deg[256];
    __shared__ int cur[256];
    __shared__ int wsum[4];
    int b = blockIdx.x;
    int t = threadIdx.x;
    int lo = b << 8;
    int nloc = N - lo; if (nloc > 256) nloc = 256;
    int e0 = bktBase[b], e1 = bktBase[b + 1];
    deg[t] = 0;
    __syncthreads();
    for (int e = e0 + t; e < e1; e += 256)
        atomicAdd(&deg[(int)pairs[e].y - lo], 1);
    __syncthreads();
    int v = deg[t];
    int lane = t & 63, w = t >> 6;
    int inc = v;
    for (int d = 1; d < 64; d <<= 1) { int tt = __shfl_up(inc, d); if (lane >= d) inc += tt; }
    if (lane == 63) wsum[w] = inc;
    __syncthreads();
    if (t == 0) { int r = 0; for (int k = 0; k < 4; ++k) { int x = wsum[k]; wsum[k] = r; r += x; } }
    __syncthreads();
    int excl = (inc - v) + wsum[w];
    if (t < nloc) off[lo + t] = e0 + excl;
    cur[t] = excl;
    if (b == 0 && t == 0) off[N] = E;
    __syncthreads();
    for (int e = e0 + t; e < e1; e += 256) {
        uint2 p = pairs[e];
        int pos = atomicAdd(&cur[(int)p.y - lo], 1);
        csr[e0 + pos] = (int)p.x;
    }
}

// ---------------------------------------------------------------------------
// prep: Wl -> bf16, (Wr+Ws) -> bf16, bias = bl+bs (f32)
// ---------------------------------------------------------------------------
__global__ void prep_kernel(const float* __restrict__ Wl0, const float* __restrict__ Wr0,
                            const float* __restrict__ Ws0, const float* __restrict__ bl0,
                            const float* __restrict__ bs0,
                            const float* __restrict__ Wl1, const float* __restrict__ Wr1,
                            const float* __restrict__ Ws1, const float* __restrict__ bl1,
                            const float* __restrict__ bs1,
                            const float* __restrict__ Wl2, const float* __restrict__ Wr2,
                            const float* __restrict__ Ws2, const float* __restrict__ bl2,
                            const float* __restrict__ bs2,
                            unsigned short* __restrict__ wlb,
                            unsigned short* __restrict__ wcb,
                            float* __restrict__ bias) {
    int i = blockIdx.x * blockDim.x + threadIdx.x;
    if (i < 3 * FEAT * FEAT) {
        int li = i >> 12, j = i & 4095;
        const float* Wl = (li == 0) ? Wl0 : (li == 1) ? Wl1 : Wl2;
        const float* Wr = (li == 0) ? Wr0 : (li == 1) ? Wr1 : Wr2;
        const float* Ws = (li == 0) ? Ws0 : (li == 1) ? Ws1 : Ws2;
        wlb[i] = f2bf(Wl[j]);
        wcb[i] = f2bf(Wr[j] + Ws[j]);
    }
    if (i < 3 * FEAT) {
        int li = i >> 6, j = i & 63;
        const float* bl = (li == 0) ? bl0 : (li == 1) ? bl1 : bl2;
        const float* bs = (li == 0) ? bs0 : (li == 1) ? bs1 : bs2;
        bias[i] = bl[j] + bs[j];
    }
}

// ---------------------------------------------------------------------------
// x (f32) -> xb (bf16), 8 elems/thread
// ---------------------------------------------------------------------------
__global__ __launch_bounds__(256) void conv_kernel(const float* __restrict__ in,
                                                   unsigned short* __restrict__ outb,
                                                   int nElem) {
    int base = (blockIdx.x * blockDim.x + threadIdx.x) * 8;
    if (base >= nElem) return;
    float4 a = *(const float4*)(in + base);
    float4 b = *(const float4*)(in + base + 4);
    ushort4 p0 = {f2bf(a.x), f2bf(a.y), f2bf(a.z), f2bf(a.w)};
    ushort4 p1 = {f2bf(b.x), f2bf(b.y), f2bf(b.z), f2bf(b.w)};
    *(ushort4*)(outb + base) = p0;
    *(ushort4*)(outb + base + 4) = p1;
}

// ---------------------------------------------------------------------------
// Max-aggregation on bf16 rows (128 B/row): 8-lane group per node.
// ---------------------------------------------------------------------------
__global__ __launch_bounds__(256) void agg_kernel(const unsigned short* __restrict__ hb,
                                                  const int* __restrict__ off,
                                                  const int* __restrict__ csr_src,
                                                  unsigned short* __restrict__ ab,
                                                  int nNodes) {
    int gid = blockIdx.x * blockDim.x + threadIdx.x;
    int n = gid >> 3;
    int q = gid & 7;
    if (n >= nNodes) return;

    int e0 = off[n], e1 = off[n + 1];
    const float NEG = -INFINITY;
    float acc[8] = {NEG, NEG, NEG, NEG, NEG, NEG, NEG, NEG};

    int e = e0;
    for (; e + 4 <= e1; e += 4) {
        int s0 = csr_src[e], s1 = csr_src[e + 1], s2 = csr_src[e + 2], s3 = csr_src[e + 3];
        uint4 v0 = *(const uint4*)&hb[(size_t)s0 * FEAT + q * 8];
        uint4 v1 = *(const uint4*)&hb[(size_t)s1 * FEAT + q * 8];
        uint4 v2 = *(const uint4*)&hb[(size_t)s2 * FEAT + q * 8];
        uint4 v3 = *(const uint4*)&hb[(size_t)s3 * FEAT + q * 8];
#define ACCUM(v)                                            \
        acc[0] = fmaxf(acc[0], bf_lo(v.x)); acc[1] = fmaxf(acc[1], bf_hi(v.x)); \
        acc[2] = fmaxf(acc[2], bf_lo(v.y)); acc[3] = fmaxf(acc[3], bf_hi(v.y)); \
        acc[4] = fmaxf(acc[4], bf_lo(v.z)); acc[5] = fmaxf(acc[5], bf_hi(v.z)); \
        acc[6] = fmaxf(acc[6], bf_lo(v.w)); acc[7] = fmaxf(acc[7], bf_hi(v.w));
        ACCUM(v0) ACCUM(v1) ACCUM(v2) ACCUM(v3)
    }
    for (; e < e1; ++e) {
        int s0 = csr_src[e];
        uint4 v0 = *(const uint4*)&hb[(size_t)s0 * FEAT + q * 8];
        ACCUM(v0)
    }
#undef ACCUM

    uint4 outv;
    if (e1 > e0) {
        outv.x = pack_exact(acc[0], acc[1]);
        outv.y = pack_exact(acc[2], acc[3]);
        outv.z = pack_exact(acc[4], acc[5]);
        outv.w = pack_exact(acc[6], acc[7]);
    } else {
        outv = make_uint4(0, 0, 0, 0);
    }
    *(uint4*)&ab[(size_t)n * FEAT + q * 8] = outv;
}

// ---------------------------------------------------------------------------
// MFMA transform: out[n][f] = relu(sum_k agg[n][k]*Wl[f][k] + h[n][k]*Wc[f][k]
//                                  + bias[f])
// Block = 4 waves; wave w = f-quarter w (f0 = w*16). Each block owns a
// contiguous range of 16-node tiles -> data reuse is intra-block (L1-hot).
// Per tile: 4x mfma_f32_16x16x32_bf16 (2 K-halves x 2 matrices), no LDS.
// A-frag (weights): lane l -> W[f0+(l&15)][(l>>4)*8 + j (+32)]
// B-frag (data):    lane l -> row[nb+(l&15)][(l>>4)*8 + j (+32)]
// C/D (guide m89):  lane l -> n = nb+(l&15), f = f0+(l>>4)*4+reg
// ---------------------------------------------------------------------------
template <bool BF16OUT>
__global__ __launch_bounds__(256) void transform_mfma_kernel(
        const unsigned short* __restrict__ hb,
        const unsigned short* __restrict__ ab,
        const unsigned short* __restrict__ Wlb,
        const unsigned short* __restrict__ Wcb,
        const float* __restrict__ bias,
        float* __restrict__ outf,
        unsigned short* __restrict__ outb,
        int nNodes, int tpb, int nTiles) {
    int wave = threadIdx.x >> 6;
    int lane = threadIdx.x & 63;
    int f0 = wave << 4;
    int lm = lane & 15;
    int lk = lane >> 4;

    // weight fragments: loaded once per wave
    short8 aWl0 = *(const short8*)&Wlb[(f0 + lm) * FEAT + lk * 8];
    short8 aWl1 = *(const short8*)&Wlb[(f0 + lm) * FEAT + lk * 8 + 32];
    short8 aWc0 = *(const short8*)&Wcb[(f0 + lm) * FEAT + lk * 8];
    short8 aWc1 = *(const short8*)&Wcb[(f0 + lm) * FEAT + lk * 8 + 32];
    f32x4 b4 = *(const f32x4*)&bias[f0 + lk * 4];

    int t0 = blockIdx.x * tpb;
    int t1 = t0 + tpb; if (t1 > nTiles) t1 = nTiles;
#pragma unroll 2
    for (int t = t0; t < t1; ++t) {
        int nb = t << 4;
        int n = nb + lm;
        int nr = (n < nNodes) ? n : (nNodes - 1);
        const unsigned short* __restrict__ ar = ab + (size_t)nr * FEAT;
        const unsigned short* __restrict__ hr = hb + (size_t)nr * FEAT;
        short8 bA0 = *(const short8*)(ar + lk * 8);
        short8 bA1 = *(const short8*)(ar + lk * 8 + 32);
        short8 bH0 = *(const short8*)(hr + lk * 8);
        short8 bH1 = *(const short8*)(hr + lk * 8 + 32);

        f32x4 acc = {0.f, 0.f, 0.f, 0.f};
        acc = __builtin_amdgcn_mfma_f32_16x16x32_bf16(aWl0, bA0, acc, 0, 0, 0);
        acc = __builtin_amdgcn_mfma_f32_16x16x32_bf16(aWl1, bA1, acc, 0, 0, 0);
        acc = __builtin_amdgcn_mfma_f32_16x16x32_bf16(aWc0, bH0, acc, 0, 0, 0);
        acc = __builtin_amdgcn_mfma_f32_16x16x32_bf16(aWc1, bH1, acc, 0, 0, 0);

        if (n < nNodes) {
            float v0 = fmaxf(acc[0] + b4[0], 0.f);
            float v1 = fmaxf(acc[1] + b4[1], 0.f);
            float v2 = fmaxf(acc[2] + b4[2], 0.f);
            float v3 = fmaxf(acc[3] + b4[3], 0.f);
            if (BF16OUT) {
                ushort4 p = {f2bf(v0), f2bf(v1), f2bf(v2), f2bf(v3)};
                *(ushort4*)&outb[(size_t)n * FEAT + f0 + lk * 4] = p;
            } else {
                float4 p = make_float4(v0, v1, v2, v3);
                *(float4*)&outf[(size_t)n * FEAT + f0 + lk * 4] = p;
            }
        }
    }
}

// ---------------------------------------------------------------------------
extern "C" void kernel_launch(void* const* d_in, const int* in_sizes, int n_in,
                              void* d_out, int out_size, void* d_ws, size_t ws_size,
                              hipStream_t stream) {
    const float* x   = (const float*)d_in[0];
    const int* eidx  = (const int*)d_in[1];
    const int N  = in_sizes[0] / FEAT;
    const int E  = in_sizes[1] / 2;
    const int* src = eidx;
    const int* dst = eidx + E;

    const float* Wl[3]; const float* bl[3]; const float* Wr[3];
    const float* Ws[3]; const float* bs[3];
    for (int li = 0; li < 3; ++li) {
        Wl[li] = (const float*)d_in[2 + 5 * li + 0];
        bl[li] = (const float*)d_in[2 + 5 * li + 1];
        Wr[li] = (const float*)d_in[2 + 5 * li + 2];
        Ws[li] = (const float*)d_in[2 + 5 * li + 3];
        bs[li] = (const float*)d_in[2 + 5 * li + 4];
    }

    auto align256 = [](size_t v) { return (v + 255) & ~(size_t)255; };
    char* ws = (char*)d_ws;
    int* off       = (int*)ws;  ws += align256((size_t)(N + 1) * 4);
    int* bktCnt    = (int*)ws;  ws += align256(NB_PAD * 4);
    int* bktBase   = (int*)ws;  ws += align256((NB_PAD + 1) * 4);
    int* bktCursor = (int*)ws;  ws += align256(NB_PAD * 4);
    uint2* pairs   = (uint2*)ws; ws += align256((size_t)E * 8);
    int* csr_src   = (int*)ws;  ws += align256((size_t)E * 4);
    unsigned short* wlb = (unsigned short*)ws; ws += align256(3 * FEAT * FEAT * 2);
    unsigned short* wcb = (unsigned short*)ws; ws += align256(3 * FEAT * FEAT * 2);
    float* biasbuf = (float*)ws; ws += align256(3 * FEAT * 4);
    unsigned short* xb  = (unsigned short*)ws; ws += align256((size_t)N * FEAT * 2);
    unsigned short* ab  = (unsigned short*)ws; ws += align256((size_t)N * FEAT * 2);
    unsigned short* h1b = (unsigned short*)ws; ws += align256((size_t)N * FEAT * 2);
    unsigned short* h2b = (unsigned short*)ws; ws += align256((size_t)N * FEAT * 2);

    const int TB = 256;
    int nBkt = (N + 255) >> 8;

    // ---- CSR build: hist -> scan -> partition -> per-bucket finalize ----
    zero_kernel<<<2, TB, 0, stream>>>(bktCnt, NB_PAD);
    hist_kernel<<<256, TB, 0, stream>>>(dst, bktCnt, E);
    bucket_scan_kernel<<<1, TB, 0, stream>>>(bktCnt, bktBase, bktCursor);
    partition_kernel<<<256, TB, 0, stream>>>(src, dst, bktCursor, pairs, E);
    csr_bucket_kernel<<<nBkt, TB, 0, stream>>>(pairs, bktBase, off, csr_src, N, E);

    prep_kernel<<<(3 * FEAT * FEAT + TB - 1) / TB, TB, 0, stream>>>(
        Wl[0], Wr[0], Ws[0], bl[0], bs[0],
        Wl[1], Wr[1], Ws[1], bl[1], bs[1],
        Wl[2], Wr[2], Ws[2], bl[2], bs[2], wlb, wcb, biasbuf);
    int convBlocks = (N * FEAT / 8 + TB - 1) / TB;
    conv_kernel<<<convBlocks, TB, 0, stream>>>(x, xb, N * FEAT);

    int aggBlocks = (N * 8 + TB - 1) / TB;
    int nTiles16 = (N + 15) / 16;
    const int TPB = 4;                               // 16-node tiles per block
    int trfBlocks = (nTiles16 + TPB - 1) / TPB;

    // ---- layer 0 ----
    agg_kernel<<<aggBlocks, TB, 0, stream>>>(xb, off, csr_src, ab, N);
    transform_mfma_kernel<true><<<trfBlocks, TB, 0, stream>>>(
        xb, ab, wlb + 0 * 4096, wcb + 0 * 4096, biasbuf + 0 * 64, nullptr, h1b, N, TPB, nTiles16);
    // ---- layer 1 ----
    agg_kernel<<<aggBlocks, TB, 0, stream>>>(h1b, off, csr_src, ab, N);
    transform_mfma_kernel<true><<<trfBlocks, TB, 0, stream>>>(
        h1b, ab, wlb + 1 * 4096, wcb + 1 * 4096, biasbuf + 1 * 64, nullptr, h2b, N, TPB, nTiles16);
    // ---- layer 2 (f32 output) ----
    agg_kernel<<<aggBlocks, TB, 0, stream>>>(h2b, off, csr_src, ab, N);
    transform_mfma_kernel<false><<<trfBlocks, TB, 0, stream>>>(
        h2b, ab, wlb + 2 * 4096, wcb + 2 * 4096, biasbuf + 2 * 64, (float*)d_out, nullptr, N, TPB, nTiles16);
}